// Round 8
// baseline (2534.503 us; speedup 1.0000x reference)
//
#include <hip/hip_runtime.h>
#include <math.h>

// Problem constants: B=4,S=2048 -> T=8192 tokens
#define KT 8192
#define KD 1024
#define KE 8
#define KF 4096
#define KNG 9        // 8 routed experts + 1 shared "expert"
#define KBM 128
#define KBN 128
#define KBK 64       // K-tile (bf16), 2 MFMA K-steps of 32
#define KMAXRT 208   // worst-case row tiles: routed <=136, shared 64 -> 200

typedef unsigned short u16t;
typedef __attribute__((ext_vector_type(8))) short short8v;  // 8 bf16 = 4 VGPR (guide §3)
typedef __attribute__((ext_vector_type(4))) float f32x4;
typedef __attribute__((ext_vector_type(4))) float fvec4;

__device__ __forceinline__ u16t f2bf(float f) {
  unsigned u = __float_as_uint(f);
  u += 0x7FFFu + ((u >> 16) & 1u);   // RNE
  return (u16t)(u >> 16);
}
__device__ __forceinline__ unsigned pack2(float lo, float hi) {
  return (unsigned)f2bf(lo) | ((unsigned)f2bf(hi) << 16);
}
// XOR-swizzled LDS index (bf16 units) for [128][KBK] tiles: 16B quad rotated by row&7.
// Conflict-free for both 16-row-stride fragment reads and row-major staging writes.
__device__ __forceinline__ int swzIdx(int r, int k) {
  return r * KBK + ((((k >> 3) ^ (r & 7))) << 3) + (k & 7);
}

// ---------------- Router: one wave per token (exact fp32) ----------------
__global__ void router_kernel(const float* __restrict__ x,
                              const float* __restrict__ wr,
                              int* __restrict__ hdr,
                              int* __restrict__ tok,
                              float* __restrict__ wgt) {
  const int t = (blockIdx.x * blockDim.x + threadIdx.x) >> 6;
  const int lane = threadIdx.x & 63;
  if (t >= KT) return;
  const float* xr = x + (size_t)t * KD;
  float acc[KE];
#pragma unroll
  for (int e = 0; e < KE; ++e) acc[e] = 0.f;
  for (int d = lane; d < KD; d += 64) {
    float xv = xr[d];
    const float* w = wr + d * KE;
    fvec4 w0 = *(const fvec4*)(w);
    fvec4 w1 = *(const fvec4*)(w + 4);
#pragma unroll
    for (int e = 0; e < 4; ++e) {
      acc[e]     = fmaf(xv, w0[e], acc[e]);
      acc[e + 4] = fmaf(xv, w1[e], acc[e + 4]);
    }
  }
#pragma unroll
  for (int e = 0; e < KE; ++e)
#pragma unroll
    for (int off = 32; off; off >>= 1) acc[e] += __shfl_xor(acc[e], off, 64);
  if (lane == 0) {
    float mx = acc[0];
#pragma unroll
    for (int e = 1; e < KE; ++e) mx = fmaxf(mx, acc[e]);
    float p[KE]; float z = 0.f;
#pragma unroll
    for (int e = 0; e < KE; ++e) { p[e] = expf(acc[e] - mx); z += p[e]; }
    float inv = 1.f / z;
#pragma unroll
    for (int e = 0; e < KE; ++e) p[e] *= inv;
    int i1 = 0; float p1 = p[0];
#pragma unroll
    for (int e = 1; e < KE; ++e) if (p[e] > p1) { p1 = p[e]; i1 = e; }
    int i2 = -1; float p2 = -1.f;
#pragma unroll
    for (int e = 0; e < KE; ++e) if (e != i1 && p[e] > p2) { p2 = p[e]; i2 = e; }
    float s = 1.f / (p1 + p2 + 1e-8f);
    int s1 = atomicAdd(&hdr[i1], 1);
    tok[i1 * KT + s1] = t; wgt[i1 * KT + s1] = p1 * s;
    int s2 = atomicAdd(&hdr[i2], 1);
    tok[i2 * KT + s2] = t; wgt[i2 * KT + s2] = p2 * s;
    tok[KE * KT + t] = t; wgt[KE * KT + t] = 1.f;  // shared group
  }
}

// ---------------- Finalize: prefix sums ----------------
__global__ void finalize_kernel(int* __restrict__ hdr) {
  if (threadIdx.x == 0 && blockIdx.x == 0) {
    hdr[KE] = KT;
    int off = 0, tb = 0;
    for (int g = 0; g < KNG; ++g) {
      hdr[16 + g] = off;
      hdr[32 + g] = tb;
      int c = hdr[g];
      off += c;
      tb += (c + KBM - 1) / KBM;
    }
    hdr[16 + KNG] = off;
    hdr[32 + KNG] = tb;
  }
}

// ---------------- Phase 1: h = silu(X@Wg) * (X@Wu), bf16 MFMA ----------------
__global__ __launch_bounds__(256, 2) void phase1_kernel(
    const float* __restrict__ x, const float* __restrict__ wg_all,
    const float* __restrict__ wu_all, const float* __restrict__ wsg,
    const float* __restrict__ wsu, const int* __restrict__ hdr,
    const int* __restrict__ tok, u16t* __restrict__ h) {
  const int* tb = hdr + 32;
  const int rt = blockIdx.x;
  if (rt >= tb[KNG]) return;
  int g = 0;
  while (rt >= tb[g + 1]) ++g;
  const int ng = hdr[g];
  const int row0 = (rt - tb[g]) * KBM;
  const int offg = hdr[16 + g];
  const int f0 = blockIdx.y * KBN;
  const float* wg = (g < KE) ? wg_all + (size_t)g * KD * KF : wsg;
  const float* wu = (g < KE) ? wu_all + (size_t)g * KD * KF : wsu;

  __shared__ u16t As[KBM * KBK];
  __shared__ u16t Bg[KBN * KBK];
  __shared__ u16t Bu[KBN * KBK];
  __shared__ int toks_s[KBM];

  const int tid = threadIdx.x;
  if (tid < KBM) {
    int gr = row0 + tid;
    if (gr >= ng) gr = ng - 1;
    toks_s[tid] = tok[g * KT + gr];
  }
  __syncthreads();

  // staging roles
  const int am = tid & 127, ah = tid >> 7;            // A: row am, k-half ah
  const int bk = (tid & 31) * 2, bn0 = (tid >> 5) * 16;  // B: k-pair bk, n-range bn0..+15
  // wave/fragment roles
  const int lane = tid & 63, wv = tid >> 6;
  const int wm = (wv & 1) * 64, wn = (wv >> 1) * 64;
  const int lr = lane & 15, lq = lane >> 4;

  f32x4 accg[4][4], accu[4][4];
#pragma unroll
  for (int i = 0; i < 4; ++i)
#pragma unroll
    for (int j = 0; j < 4; ++j) { accg[i][j] = (f32x4)(0.f); accu[i][j] = (f32x4)(0.f); }

  const float* xrow = x + (size_t)toks_s[am] * KD;

  for (int k0 = 0; k0 < KD; k0 += KBK) {
    // --- A stage: [128][64] fp32 -> bf16, linear-k, swizzled quads
    {
      const float* src = xrow + k0 + ah * 32;
#pragma unroll
      for (int j8 = 0; j8 < 4; ++j8) {
        fvec4 v0 = *(const fvec4*)(src + j8 * 8);
        fvec4 v1 = *(const fvec4*)(src + j8 * 8 + 4);
        unsigned* dst = (unsigned*)&As[swzIdx(am, ah * 32 + j8 * 8)];
        dst[0] = pack2(v0[0], v0[1]);
        dst[1] = pack2(v0[2], v0[3]);
        dst[2] = pack2(v1[0], v1[1]);
        dst[3] = pack2(v1[2], v1[3]);
      }
    }
    // --- B stage: transpose [64][128] fp32 -> Bs[n][k] bf16 (k-pairs as u32)
    {
      const float* g0p = wg + (size_t)(k0 + bk) * KF + f0 + bn0;
      const float* g1p = g0p + KF;
      const float* u0p = wu + (size_t)(k0 + bk) * KF + f0 + bn0;
      const float* u1p = u0p + KF;
#pragma unroll
      for (int q = 0; q < 4; ++q) {
        fvec4 a0 = *(const fvec4*)(g0p + q * 4);
        fvec4 a1 = *(const fvec4*)(g1p + q * 4);
        fvec4 c0 = *(const fvec4*)(u0p + q * 4);
        fvec4 c1 = *(const fvec4*)(u1p + q * 4);
#pragma unroll
        for (int j = 0; j < 4; ++j) {
          int n = bn0 + q * 4 + j;
          int idx = swzIdx(n, bk);  // bk even -> 4B aligned
          *(unsigned*)&Bg[idx] = pack2(a0[j], a1[j]);
          *(unsigned*)&Bu[idx] = pack2(c0[j], c1[j]);
        }
      }
    }
    __syncthreads();
#pragma unroll
    for (int kk = 0; kk < 2; ++kk) {
      const int kb = kk * 32 + lq * 8;
      short8v av[4];
#pragma unroll
      for (int mi = 0; mi < 4; ++mi)
        av[mi] = *(const short8v*)&As[swzIdx(wm + mi * 16 + lr, kb)];
#pragma unroll
      for (int ni = 0; ni < 4; ++ni) {
        short8v bgv = *(const short8v*)&Bg[swzIdx(wn + ni * 16 + lr, kb)];
        short8v buv = *(const short8v*)&Bu[swzIdx(wn + ni * 16 + lr, kb)];
#pragma unroll
        for (int mi = 0; mi < 4; ++mi) {
          accg[mi][ni] = __builtin_amdgcn_mfma_f32_16x16x32_bf16(av[mi], bgv, accg[mi][ni], 0, 0, 0);
          accu[mi][ni] = __builtin_amdgcn_mfma_f32_16x16x32_bf16(av[mi], buv, accu[mi][ni], 0, 0, 0);
        }
      }
    }
    __syncthreads();
  }

  // --- epilogue: silu(g)*u -> h (bf16). C/D: col=lane&15, row=(lane>>4)*4+reg
#pragma unroll
  for (int mi = 0; mi < 4; ++mi)
#pragma unroll
    for (int r = 0; r < 4; ++r) {
      int gr = row0 + wm + mi * 16 + lq * 4 + r;
      if (gr >= ng) continue;
      u16t* hp = h + (size_t)(offg + gr) * KF + f0 + wn + lr;
#pragma unroll
      for (int ni = 0; ni < 4; ++ni) {
        float gv = accg[mi][ni][r];
        float uv = accu[mi][ni][r];
        float sv = gv / (1.f + __expf(-gv));
        hp[ni * 16] = f2bf(sv * uv);
      }
    }
}

// ---------------- Phase 2: out += w * (h @ Wd), bf16 MFMA ----------------
__global__ __launch_bounds__(256, 2) void phase2_kernel(
    const u16t* __restrict__ h, const float* __restrict__ wd_all,
    const float* __restrict__ wsd, const int* __restrict__ hdr,
    const int* __restrict__ tok, const float* __restrict__ wgt,
    float* __restrict__ out) {
  const int* tb = hdr + 32;
  const int rt = blockIdx.x;
  if (rt >= tb[KNG]) return;
  int g = 0;
  while (rt >= tb[g + 1]) ++g;
  const int ng = hdr[g];
  const int row0 = (rt - tb[g]) * KBM;
  const int offg = hdr[16 + g];
  const int d0 = blockIdx.y * KBN;
  const float* wd = (g < KE) ? wd_all + (size_t)g * KF * KD : wsd;

  __shared__ u16t As[KBM * KBK];
  __shared__ u16t Bs[KBN * KBK];
  __shared__ int toks_s[KBM];
  __shared__ float wgts_s[KBM];

  const int tid = threadIdx.x;
  if (tid < KBM) {
    int gr = row0 + tid;
    int grc = (gr >= ng) ? ng - 1 : gr;
    toks_s[tid] = tok[g * KT + grc];
    wgts_s[tid] = wgt[g * KT + grc];
  }
  __syncthreads();

  const int am = tid & 127, ah = tid >> 7;
  const int bk = (tid & 31) * 2, bn0 = (tid >> 5) * 16;
  const int lane = tid & 63, wv = tid >> 6;
  const int wm = (wv & 1) * 64, wn = (wv >> 1) * 64;
  const int lr = lane & 15, lq = lane >> 4;

  f32x4 acc[4][4];
#pragma unroll
  for (int i = 0; i < 4; ++i)
#pragma unroll
    for (int j = 0; j < 4; ++j) acc[i][j] = (f32x4)(0.f);

  int gra = row0 + am;
  if (gra >= ng) gra = ng - 1;
  const u16t* hrow = h + (size_t)(offg + gra) * KF;

  for (int k0 = 0; k0 < KF; k0 += KBK) {
    // --- A stage: h already bf16, straight 16B copies into swizzled quads
    {
      const u16t* src = hrow + k0 + ah * 32;
#pragma unroll
      for (int j8 = 0; j8 < 4; ++j8) {
        short8v v = *(const short8v*)(src + j8 * 8);
        *(short8v*)&As[swzIdx(am, ah * 32 + j8 * 8)] = v;
      }
    }
    // --- B stage: transpose [64][128] fp32 Wd -> Bs[n][k] bf16
    {
      const float* d0p = wd + (size_t)(k0 + bk) * KD + d0 + bn0;
      const float* d1p = d0p + KD;
#pragma unroll
      for (int q = 0; q < 4; ++q) {
        fvec4 a0 = *(const fvec4*)(d0p + q * 4);
        fvec4 a1 = *(const fvec4*)(d1p + q * 4);
#pragma unroll
        for (int j = 0; j < 4; ++j) {
          int n = bn0 + q * 4 + j;
          *(unsigned*)&Bs[swzIdx(n, bk)] = pack2(a0[j], a1[j]);
        }
      }
    }
    __syncthreads();
#pragma unroll
    for (int kk = 0; kk < 2; ++kk) {
      const int kb = kk * 32 + lq * 8;
      short8v av[4];
#pragma unroll
      for (int mi = 0; mi < 4; ++mi)
        av[mi] = *(const short8v*)&As[swzIdx(wm + mi * 16 + lr, kb)];
#pragma unroll
      for (int ni = 0; ni < 4; ++ni) {
        short8v bv = *(const short8v*)&Bs[swzIdx(wn + ni * 16 + lr, kb)];
#pragma unroll
        for (int mi = 0; mi < 4; ++mi)
          acc[mi][ni] = __builtin_amdgcn_mfma_f32_16x16x32_bf16(av[mi], bv, acc[mi][ni], 0, 0, 0);
      }
    }
    __syncthreads();
  }

  // --- epilogue: weighted atomic accumulate into out
#pragma unroll
  for (int mi = 0; mi < 4; ++mi)
#pragma unroll
    for (int r = 0; r < 4; ++r) {
      int row = wm + mi * 16 + lq * 4 + r;
      int gr = row0 + row;
      if (gr >= ng) continue;
      int t = toks_s[row];
      float w = wgts_s[row];
      float* op = out + (size_t)t * KD + d0 + wn + lr;
#pragma unroll
      for (int ni = 0; ni < 4; ++ni)
        atomicAdd(op + ni * 16, acc[mi][ni][r] * w);
    }
}

extern "C" void kernel_launch(void* const* d_in, const int* in_sizes, int n_in,
                              void* d_out, int out_size, void* d_ws, size_t ws_size,
                              hipStream_t stream) {
  const float* x        = (const float*)d_in[0];
  const float* w_router = (const float*)d_in[1];
  const float* w_gate   = (const float*)d_in[2];
  const float* w_up     = (const float*)d_in[3];
  const float* w_down   = (const float*)d_in[4];
  const float* ws_gate  = (const float*)d_in[5];
  const float* ws_up    = (const float*)d_in[6];
  const float* ws_down  = (const float*)d_in[7];

  char* ws = (char*)d_ws;
  int* hdr = (int*)ws;
  int* tok = (int*)(ws + 1024);
  float* wgt = (float*)(ws + 1024 + (size_t)KNG * KT * 4);
  const size_t hoff = 1024 + (size_t)2 * KNG * KT * 4;   // 590848 (16B aligned)
  const size_t rows = (size_t)3 * KT;                    // 24576 h-rows
  const size_t need = hoff + rows * KF * 2;              // ~202 MB (bf16 h)

  hipMemsetAsync(hdr, 0, 1024, stream);
  hipMemsetAsync(d_out, 0, (size_t)out_size * sizeof(float), stream);

  router_kernel<<<KT / 4, 256, 0, stream>>>(x, w_router, hdr, tok, wgt);
  finalize_kernel<<<1, 64, 0, stream>>>(hdr);

  if (ws_size >= need) {
    u16t* h = (u16t*)(ws + hoff);
    dim3 blk(256);
    dim3 g1(KMAXRT, KF / KBN);  // (208, 32)
    dim3 g2(KMAXRT, KD / KBN);  // (208, 8)
    phase1_kernel<<<g1, blk, 0, stream>>>(x, w_gate, w_up, ws_gate, ws_up, hdr, tok, h);
    phase2_kernel<<<g2, blk, 0, stream>>>(h, w_down, ws_down, hdr, tok, wgt, (float*)d_out);
  }
  // else: ws too small -> loud validation failure tells us to fuse phases.
}

// Round 10
// 1442.902 us; speedup vs baseline: 1.7565x; 1.7565x over previous
//
#include <hip/hip_runtime.h>
#include <math.h>

// Problem constants: B=4,S=2048 -> T=8192 tokens
#define KT 8192
#define KD 1024
#define KE 8
#define KF 4096
#define KNG 9        // 8 routed experts + 1 shared "expert"
#define KBM 128
#define KBN 128
#define KBK 64       // K-tile (bf16), 2 MFMA K-steps of 32
#define KMAXRT 208   // worst-case row tiles: routed <=136, shared 64 -> 200
#define MATELTS 4194304  // D*F elements per weight matrix

typedef unsigned short u16t;
typedef __attribute__((ext_vector_type(8))) short short8v;  // 8 bf16 = 4 VGPR
typedef __attribute__((ext_vector_type(4))) float f32x4;
typedef __attribute__((ext_vector_type(4))) float fvec4;

__device__ __forceinline__ u16t f2bf(float f) {
  unsigned u = __float_as_uint(f);
  u += 0x7FFFu + ((u >> 16) & 1u);   // RNE
  return (u16t)(u >> 16);
}
__device__ __forceinline__ unsigned pack2(float lo, float hi) {
  return (unsigned)f2bf(lo) | ((unsigned)f2bf(hi) << 16);
}
// XOR-swizzled LDS index (bf16 units) for [128][64] tiles: 16B quad rotated by row&7.
__device__ __forceinline__ int swzIdx(int r, int k) {
  return r * KBK + ((((k >> 3) ^ (r & 7))) << 3) + (k & 7);
}
// global -> LDS direct copy, 16B per lane (guide m97: width 16 -> global_load_lds_dwordx4)
typedef const __attribute__((address_space(1))) void* gas_ptr;
typedef __attribute__((address_space(3))) void* las_ptr;
__device__ __forceinline__ void glds16(const void* g, void* l) {
  __builtin_amdgcn_global_load_lds((gas_ptr)g, (las_ptr)l, 16, 0, 0);
}

// ---------------- Router: one wave per token (exact fp32) ----------------
__global__ void router_kernel(const float* __restrict__ x,
                              const float* __restrict__ wr,
                              int* __restrict__ hdr,
                              int* __restrict__ tok,
                              float* __restrict__ wgt) {
  const int t = (blockIdx.x * blockDim.x + threadIdx.x) >> 6;
  const int lane = threadIdx.x & 63;
  if (t >= KT) return;
  const float* xr = x + (size_t)t * KD;
  float acc[KE];
#pragma unroll
  for (int e = 0; e < KE; ++e) acc[e] = 0.f;
  for (int d = lane; d < KD; d += 64) {
    float xv = xr[d];
    const float* w = wr + d * KE;
    fvec4 w0 = *(const fvec4*)(w);
    fvec4 w1 = *(const fvec4*)(w + 4);
#pragma unroll
    for (int e = 0; e < 4; ++e) {
      acc[e]     = fmaf(xv, w0[e], acc[e]);
      acc[e + 4] = fmaf(xv, w1[e], acc[e + 4]);
    }
  }
#pragma unroll
  for (int e = 0; e < KE; ++e)
#pragma unroll
    for (int off = 32; off; off >>= 1) acc[e] += __shfl_xor(acc[e], off, 64);
  if (lane == 0) {
    float mx = acc[0];
#pragma unroll
    for (int e = 1; e < KE; ++e) mx = fmaxf(mx, acc[e]);
    float p[KE]; float z = 0.f;
#pragma unroll
    for (int e = 0; e < KE; ++e) { p[e] = expf(acc[e] - mx); z += p[e]; }
    float inv = 1.f / z;
#pragma unroll
    for (int e = 0; e < KE; ++e) p[e] *= inv;
    int i1 = 0; float p1 = p[0];
#pragma unroll
    for (int e = 1; e < KE; ++e) if (p[e] > p1) { p1 = p[e]; i1 = e; }
    int i2 = -1; float p2 = -1.f;
#pragma unroll
    for (int e = 0; e < KE; ++e) if (e != i1 && p[e] > p2) { p2 = p[e]; i2 = e; }
    float s = 1.f / (p1 + p2 + 1e-8f);
    int s1 = atomicAdd(&hdr[i1], 1);
    tok[i1 * KT + s1] = t; wgt[i1 * KT + s1] = p1 * s;
    int s2 = atomicAdd(&hdr[i2], 1);
    tok[i2 * KT + s2] = t; wgt[i2 * KT + s2] = p2 * s;
    tok[KE * KT + t] = t; wgt[KE * KT + t] = 1.f;  // shared group
  }
}

// ---------------- Finalize: prefix sums ----------------
__global__ void finalize_kernel(int* __restrict__ hdr) {
  if (threadIdx.x == 0 && blockIdx.x == 0) {
    hdr[KE] = KT;
    int off = 0, tb = 0;
    for (int g = 0; g < KNG; ++g) {
      hdr[16 + g] = off;
      hdr[32 + g] = tb;
      int c = hdr[g];
      off += c;
      tb += (c + KBM - 1) / KBM;
    }
    hdr[16 + KNG] = off;
    hdr[32 + KNG] = tb;
  }
}

// ---------------- Convert x: fp32 -> bf16 plain [t][k] ----------------
__global__ void convert_x_kernel(const float* __restrict__ x, u16t* __restrict__ xb) {
  const int i = (blockIdx.x * 256 + threadIdx.x) * 8;
  fvec4 a = *(const fvec4*)(x + i);
  fvec4 b = *(const fvec4*)(x + i + 4);
  uint4 o;
  o.x = pack2(a[0], a[1]); o.y = pack2(a[2], a[3]);
  o.z = pack2(b[0], b[1]); o.w = pack2(b[2], b[3]);
  *(uint4*)(xb + i) = o;
}

// ---------------- Convert weights: fp32 [K][N] -> bf16 tiled+transposed+preswizzled
// Output contract per 128n x 64k tile (8192 elts): chunk c = r*8+qs (16B each) holds
// Wt[n0+r][k0 + (qs^(r&7))*8 + j], j=0..7.  27 matrices x 512 tiles.
__global__ __launch_bounds__(256) void convert_w_kernel(
    const float* __restrict__ wg, const float* __restrict__ wu,
    const float* __restrict__ wd, const float* __restrict__ sg,
    const float* __restrict__ su, const float* __restrict__ sd,
    u16t* __restrict__ wpre) {
  __shared__ float ft[64][132];
  const int m = blockIdx.x >> 9;
  const int t = blockIdx.x & 511;
  const int e = m / 3, ty = m - e * 3;
  const float* src; int K, N;
  if (ty == 2)      { K = KF; N = KD; src = (e < 8) ? wd + (size_t)e * MATELTS : sd; }
  else if (ty == 0) { K = KD; N = KF; src = (e < 8) ? wg + (size_t)e * MATELTS : sg; }
  else              { K = KD; N = KF; src = (e < 8) ? wu + (size_t)e * MATELTS : su; }
  const int ntk = K >> 6;
  const int tn = t / ntk, tk = t - tn * ntk;
  const int n0 = tn << 7, k0 = tk << 6;
  const int tid = threadIdx.x;
  const int kk0 = tid >> 5, nn4 = (tid & 31) << 2;
#pragma unroll
  for (int it = 0; it < 8; ++it) {
    int kk = kk0 + it * 8;
    fvec4 v = *(const fvec4*)(src + (size_t)(k0 + kk) * N + n0 + nn4);
    ft[kk][nn4] = v[0]; ft[kk][nn4 + 1] = v[1];
    ft[kk][nn4 + 2] = v[2]; ft[kk][nn4 + 3] = v[3];
  }
  __syncthreads();
  u16t* dst = wpre + (size_t)m * MATELTS + (size_t)t * 8192;
#pragma unroll
  for (int p = 0; p < 4; ++p) {
    int c = p * 256 + tid;
    int r = c >> 3, qs = c & 7, kq = qs ^ (r & 7);
    uint4 o;
    o.x = pack2(ft[kq * 8 + 0][r], ft[kq * 8 + 1][r]);
    o.y = pack2(ft[kq * 8 + 2][r], ft[kq * 8 + 3][r]);
    o.z = pack2(ft[kq * 8 + 4][r], ft[kq * 8 + 5][r]);
    o.w = pack2(ft[kq * 8 + 6][r], ft[kq * 8 + 7][r]);
    *(uint4*)(dst + c * 8) = o;
  }
}

// ---------------- FAST Phase 1: h = silu(X@Wg)*(X@Wu), glds staging ----------------
__global__ __launch_bounds__(256, 2) void phase1f_kernel(
    const u16t* __restrict__ xb, const u16t* __restrict__ wpre,
    const int* __restrict__ hdr, const int* __restrict__ tok,
    u16t* __restrict__ h) {
  const int* tb = hdr + 32;
  const int rt = blockIdx.x;
  if (rt >= tb[KNG]) return;
  int g = 0;
  while (rt >= tb[g + 1]) ++g;
  const int ng = hdr[g];
  const int row0 = (rt - tb[g]) * KBM;
  const int offg = hdr[16 + g];
  const int f0 = blockIdx.y * KBN;

  __shared__ u16t As[KBM * KBK];
  __shared__ u16t Bg[KBN * KBK];
  __shared__ u16t Bu[KBN * KBK];
  __shared__ int toks_s[KBM];

  const int tid = threadIdx.x;
  if (tid < KBM) {
    int gr = row0 + tid;
    if (gr >= ng) gr = ng - 1;
    toks_s[tid] = tok[g * KT + gr];
  }
  __syncthreads();

  const int lane = tid & 63, wv = tid >> 6;
  const int wm = (wv & 1) * 64, wn = (wv >> 1) * 64;
  const int lr = lane & 15, lq = lane >> 4;
  const int cr = tid >> 3;           // A-chunk row (call adds 32)
  const int cq = tid & 7;            // A-chunk swizzled quad
  const int wvo = (tid & 192) * 8;   // wave chunk base (elements)

  // gate tile base: matrix 3g+0, n-tile f0/128, ntiles_k = 16
  const u16t* gp = wpre + (size_t)(3 * g) * MATELTS + (size_t)(f0 >> 7) * 16 * 8192;
  const u16t* up = gp + MATELTS;

  f32x4 accg[4][4], accu[4][4];
#pragma unroll
  for (int i = 0; i < 4; ++i)
#pragma unroll
    for (int j = 0; j < 4; ++j) { accg[i][j] = (f32x4)(0.f); accu[i][j] = (f32x4)(0.f); }

  for (int k0i = 0; k0i < KD / KBK; ++k0i) {
    const u16t* gt = gp + (size_t)k0i * 8192;
    const u16t* ut = up + (size_t)k0i * 8192;
#pragma unroll
    for (int c4 = 0; c4 < 4; ++c4) {
      glds16(gt + (c4 * 256 + tid) * 8, (u16t*)Bg + c4 * 2048 + wvo);
      glds16(ut + (c4 * 256 + tid) * 8, (u16t*)Bu + c4 * 2048 + wvo);
      int r = c4 * 32 + cr;
      glds16(xb + (size_t)toks_s[r] * KD + k0i * KBK + ((cq ^ (r & 7)) << 3),
             (u16t*)As + c4 * 2048 + wvo);
    }
    __syncthreads();
#pragma unroll
    for (int kk = 0; kk < 2; ++kk) {
      const int kb = kk * 32 + lq * 8;
      short8v av[4];
#pragma unroll
      for (int mi = 0; mi < 4; ++mi)
        av[mi] = *(const short8v*)&As[swzIdx(wm + mi * 16 + lr, kb)];
#pragma unroll
      for (int ni = 0; ni < 4; ++ni) {
        short8v bgv = *(const short8v*)&Bg[swzIdx(wn + ni * 16 + lr, kb)];
        short8v buv = *(const short8v*)&Bu[swzIdx(wn + ni * 16 + lr, kb)];
#pragma unroll
        for (int mi = 0; mi < 4; ++mi) {
          accg[mi][ni] = __builtin_amdgcn_mfma_f32_16x16x32_bf16(av[mi], bgv, accg[mi][ni], 0, 0, 0);
          accu[mi][ni] = __builtin_amdgcn_mfma_f32_16x16x32_bf16(av[mi], buv, accu[mi][ni], 0, 0, 0);
        }
      }
    }
    __syncthreads();
  }

#pragma unroll
  for (int mi = 0; mi < 4; ++mi)
#pragma unroll
    for (int r = 0; r < 4; ++r) {
      int gr = row0 + wm + mi * 16 + lq * 4 + r;
      if (gr >= ng) continue;
      u16t* hp = h + (size_t)(offg + gr) * KF + f0 + wn + lr;
#pragma unroll
      for (int ni = 0; ni < 4; ++ni) {
        float gv = accg[mi][ni][r];
        float uv = accu[mi][ni][r];
        float sv = gv / (1.f + __expf(-gv));
        hp[ni * 16] = f2bf(sv * uv);
      }
    }
}

// ---------------- FAST Phase 2: out += w * (h @ Wd), glds staging ----------------
__global__ __launch_bounds__(256, 2) void phase2f_kernel(
    const u16t* __restrict__ h, const u16t* __restrict__ wpre,
    const int* __restrict__ hdr, const int* __restrict__ tok,
    const float* __restrict__ wgt, float* __restrict__ out) {
  const int* tb = hdr + 32;
  const int rt = blockIdx.x;
  if (rt >= tb[KNG]) return;
  int g = 0;
  while (rt >= tb[g + 1]) ++g;
  const int ng = hdr[g];
  const int row0 = (rt - tb[g]) * KBM;
  const int offg = hdr[16 + g];
  const int d0 = blockIdx.y * KBN;

  __shared__ u16t As[KBM * KBK];
  __shared__ u16t Bs[KBN * KBK];
  __shared__ int toks_s[KBM];
  __shared__ float wgts_s[KBM];

  const int tid = threadIdx.x;
  if (tid < KBM) {
    int gr = row0 + tid;
    int grc = (gr >= ng) ? ng - 1 : gr;
    toks_s[tid] = tok[g * KT + grc];
    wgts_s[tid] = wgt[g * KT + grc];
  }
  __syncthreads();

  const int lane = tid & 63, wv = tid >> 6;
  const int wm = (wv & 1) * 64, wn = (wv >> 1) * 64;
  const int lr = lane & 15, lq = lane >> 4;
  const int cr = tid >> 3;
  const int cq = tid & 7;
  const int wvo = (tid & 192) * 8;

  // down tile base: matrix 3g+2, n-tile d0/128, ntiles_k = 64
  const u16t* dp = wpre + (size_t)(3 * g + 2) * MATELTS + (size_t)(d0 >> 7) * 64 * 8192;

  f32x4 acc[4][4];
#pragma unroll
  for (int i = 0; i < 4; ++i)
#pragma unroll
    for (int j = 0; j < 4; ++j) acc[i][j] = (f32x4)(0.f);

  for (int k0i = 0; k0i < KF / KBK; ++k0i) {
    const u16t* dt = dp + (size_t)k0i * 8192;
#pragma unroll
    for (int c4 = 0; c4 < 4; ++c4) {
      glds16(dt + (c4 * 256 + tid) * 8, (u16t*)Bs + c4 * 2048 + wvo);
      int r = c4 * 32 + cr;
      int grow = row0 + r;
      if (grow >= ng) grow = ng - 1;
      glds16(h + (size_t)(offg + grow) * KF + k0i * KBK + ((cq ^ (r & 7)) << 3),
             (u16t*)As + c4 * 2048 + wvo);
    }
    __syncthreads();
#pragma unroll
    for (int kk = 0; kk < 2; ++kk) {
      const int kb = kk * 32 + lq * 8;
      short8v av[4];
#pragma unroll
      for (int mi = 0; mi < 4; ++mi)
        av[mi] = *(const short8v*)&As[swzIdx(wm + mi * 16 + lr, kb)];
#pragma unroll
      for (int ni = 0; ni < 4; ++ni) {
        short8v bv = *(const short8v*)&Bs[swzIdx(wn + ni * 16 + lr, kb)];
#pragma unroll
        for (int mi = 0; mi < 4; ++mi)
          acc[mi][ni] = __builtin_amdgcn_mfma_f32_16x16x32_bf16(av[mi], bv, acc[mi][ni], 0, 0, 0);
      }
    }
    __syncthreads();
  }

#pragma unroll
  for (int mi = 0; mi < 4; ++mi)
#pragma unroll
    for (int r = 0; r < 4; ++r) {
      int row = wm + mi * 16 + lq * 4 + r;
      int gr = row0 + row;
      if (gr >= ng) continue;
      int t = toks_s[row];
      float w = wgts_s[row];
      float* op = out + (size_t)t * KD + d0 + wn + lr;
#pragma unroll
      for (int ni = 0; ni < 4; ++ni)
        atomicAdd(op + ni * 16, acc[mi][ni][r] * w);
    }
}

// ================= SLOW PATH (round-8 proven kernels, fallback) =================
__global__ __launch_bounds__(256, 2) void phase1s_kernel(
    const float* __restrict__ x, const float* __restrict__ wg_all,
    const float* __restrict__ wu_all, const float* __restrict__ wsg,
    const float* __restrict__ wsu, const int* __restrict__ hdr,
    const int* __restrict__ tok, u16t* __restrict__ h) {
  const int* tb = hdr + 32;
  const int rt = blockIdx.x;
  if (rt >= tb[KNG]) return;
  int g = 0;
  while (rt >= tb[g + 1]) ++g;
  const int ng = hdr[g];
  const int row0 = (rt - tb[g]) * KBM;
  const int offg = hdr[16 + g];
  const int f0 = blockIdx.y * KBN;
  const float* wg = (g < KE) ? wg_all + (size_t)g * KD * KF : wsg;
  const float* wu = (g < KE) ? wu_all + (size_t)g * KD * KF : wsu;

  __shared__ u16t As[KBM * KBK];
  __shared__ u16t Bg[KBN * KBK];
  __shared__ u16t Bu[KBN * KBK];
  __shared__ int toks_s[KBM];

  const int tid = threadIdx.x;
  if (tid < KBM) {
    int gr = row0 + tid;
    if (gr >= ng) gr = ng - 1;
    toks_s[tid] = tok[g * KT + gr];
  }
  __syncthreads();

  const int am = tid & 127, ah = tid >> 7;
  const int bk = (tid & 31) * 2, bn0 = (tid >> 5) * 16;
  const int lane = tid & 63, wv = tid >> 6;
  const int wm = (wv & 1) * 64, wn = (wv >> 1) * 64;
  const int lr = lane & 15, lq = lane >> 4;

  f32x4 accg[4][4], accu[4][4];
#pragma unroll
  for (int i = 0; i < 4; ++i)
#pragma unroll
    for (int j = 0; j < 4; ++j) { accg[i][j] = (f32x4)(0.f); accu[i][j] = (f32x4)(0.f); }

  const float* xrow = x + (size_t)toks_s[am] * KD;

  for (int k0 = 0; k0 < KD; k0 += KBK) {
    {
      const float* src = xrow + k0 + ah * 32;
#pragma unroll
      for (int j8 = 0; j8 < 4; ++j8) {
        fvec4 v0 = *(const fvec4*)(src + j8 * 8);
        fvec4 v1 = *(const fvec4*)(src + j8 * 8 + 4);
        unsigned* dst = (unsigned*)&As[swzIdx(am, ah * 32 + j8 * 8)];
        dst[0] = pack2(v0[0], v0[1]);
        dst[1] = pack2(v0[2], v0[3]);
        dst[2] = pack2(v1[0], v1[1]);
        dst[3] = pack2(v1[2], v1[3]);
      }
    }
    {
      const float* g0p = wg + (size_t)(k0 + bk) * KF + f0 + bn0;
      const float* g1p = g0p + KF;
      const float* u0p = wu + (size_t)(k0 + bk) * KF + f0 + bn0;
      const float* u1p = u0p + KF;
#pragma unroll
      for (int q = 0; q < 4; ++q) {
        fvec4 a0 = *(const fvec4*)(g0p + q * 4);
        fvec4 a1 = *(const fvec4*)(g1p + q * 4);
        fvec4 c0 = *(const fvec4*)(u0p + q * 4);
        fvec4 c1 = *(const fvec4*)(u1p + q * 4);
#pragma unroll
        for (int j = 0; j < 4; ++j) {
          int n = bn0 + q * 4 + j;
          int idx = swzIdx(n, bk);
          *(unsigned*)&Bg[idx] = pack2(a0[j], a1[j]);
          *(unsigned*)&Bu[idx] = pack2(c0[j], c1[j]);
        }
      }
    }
    __syncthreads();
#pragma unroll
    for (int kk = 0; kk < 2; ++kk) {
      const int kb = kk * 32 + lq * 8;
      short8v av[4];
#pragma unroll
      for (int mi = 0; mi < 4; ++mi)
        av[mi] = *(const short8v*)&As[swzIdx(wm + mi * 16 + lr, kb)];
#pragma unroll
      for (int ni = 0; ni < 4; ++ni) {
        short8v bgv = *(const short8v*)&Bg[swzIdx(wn + ni * 16 + lr, kb)];
        short8v buv = *(const short8v*)&Bu[swzIdx(wn + ni * 16 + lr, kb)];
#pragma unroll
        for (int mi = 0; mi < 4; ++mi) {
          accg[mi][ni] = __builtin_amdgcn_mfma_f32_16x16x32_bf16(av[mi], bgv, accg[mi][ni], 0, 0, 0);
          accu[mi][ni] = __builtin_amdgcn_mfma_f32_16x16x32_bf16(av[mi], buv, accu[mi][ni], 0, 0, 0);
        }
      }
    }
    __syncthreads();
  }

#pragma unroll
  for (int mi = 0; mi < 4; ++mi)
#pragma unroll
    for (int r = 0; r < 4; ++r) {
      int gr = row0 + wm + mi * 16 + lq * 4 + r;
      if (gr >= ng) continue;
      u16t* hp = h + (size_t)(offg + gr) * KF + f0 + wn + lr;
#pragma unroll
      for (int ni = 0; ni < 4; ++ni) {
        float gv = accg[mi][ni][r];
        float uv = accu[mi][ni][r];
        float sv = gv / (1.f + __expf(-gv));
        hp[ni * 16] = f2bf(sv * uv);
      }
    }
}

__global__ __launch_bounds__(256, 2) void phase2s_kernel(
    const u16t* __restrict__ h, const float* __restrict__ wd_all,
    const float* __restrict__ wsd, const int* __restrict__ hdr,
    const int* __restrict__ tok, const float* __restrict__ wgt,
    float* __restrict__ out) {
  const int* tb = hdr + 32;
  const int rt = blockIdx.x;
  if (rt >= tb[KNG]) return;
  int g = 0;
  while (rt >= tb[g + 1]) ++g;
  const int ng = hdr[g];
  const int row0 = (rt - tb[g]) * KBM;
  const int offg = hdr[16 + g];
  const int d0 = blockIdx.y * KBN;
  const float* wd = (g < KE) ? wd_all + (size_t)g * KF * KD : wsd;

  __shared__ u16t As[KBM * KBK];
  __shared__ u16t Bs[KBN * KBK];
  __shared__ int toks_s[KBM];
  __shared__ float wgts_s[KBM];

  const int tid = threadIdx.x;
  if (tid < KBM) {
    int gr = row0 + tid;
    int grc = (gr >= ng) ? ng - 1 : gr;
    toks_s[tid] = tok[g * KT + grc];
    wgts_s[tid] = wgt[g * KT + grc];
  }
  __syncthreads();

  const int am = tid & 127, ah = tid >> 7;
  const int bk = (tid & 31) * 2, bn0 = (tid >> 5) * 16;
  const int lane = tid & 63, wv = tid >> 6;
  const int wm = (wv & 1) * 64, wn = (wv >> 1) * 64;
  const int lr = lane & 15, lq = lane >> 4;

  f32x4 acc[4][4];
#pragma unroll
  for (int i = 0; i < 4; ++i)
#pragma unroll
    for (int j = 0; j < 4; ++j) acc[i][j] = (f32x4)(0.f);

  int gra = row0 + am;
  if (gra >= ng) gra = ng - 1;
  const u16t* hrow = h + (size_t)(offg + gra) * KF;

  for (int k0 = 0; k0 < KF; k0 += KBK) {
    {
      const u16t* src = hrow + k0 + ah * 32;
#pragma unroll
      for (int j8 = 0; j8 < 4; ++j8) {
        short8v v = *(const short8v*)(src + j8 * 8);
        *(short8v*)&As[swzIdx(am, ah * 32 + j8 * 8)] = v;
      }
    }
    {
      const float* d0p = wd + (size_t)(k0 + bk) * KD + d0 + bn0;
      const float* d1p = d0p + KD;
#pragma unroll
      for (int q = 0; q < 4; ++q) {
        fvec4 a0 = *(const fvec4*)(d0p + q * 4);
        fvec4 a1 = *(const fvec4*)(d1p + q * 4);
#pragma unroll
        for (int j = 0; j < 4; ++j) {
          int n = bn0 + q * 4 + j;
          *(unsigned*)&Bs[swzIdx(n, bk)] = pack2(a0[j], a1[j]);
        }
      }
    }
    __syncthreads();
#pragma unroll
    for (int kk = 0; kk < 2; ++kk) {
      const int kb = kk * 32 + lq * 8;
      short8v av[4];
#pragma unroll
      for (int mi = 0; mi < 4; ++mi)
        av[mi] = *(const short8v*)&As[swzIdx(wm + mi * 16 + lr, kb)];
#pragma unroll
      for (int ni = 0; ni < 4; ++ni) {
        short8v bv = *(const short8v*)&Bs[swzIdx(wn + ni * 16 + lr, kb)];
#pragma unroll
        for (int mi = 0; mi < 4; ++mi)
          acc[mi][ni] = __builtin_amdgcn_mfma_f32_16x16x32_bf16(av[mi], bv, acc[mi][ni], 0, 0, 0);
      }
    }
    __syncthreads();
  }

#pragma unroll
  for (int mi = 0; mi < 4; ++mi)
#pragma unroll
    for (int r = 0; r < 4; ++r) {
      int row = wm + mi * 16 + lq * 4 + r;
      int gr = row0 + row;
      if (gr >= ng) continue;
      int t = toks_s[row];
      float w = wgts_s[row];
      float* op = out + (size_t)t * KD + d0 + wn + lr;
#pragma unroll
      for (int ni = 0; ni < 4; ++ni)
        atomicAdd(op + ni * 16, acc[mi][ni][r] * w);
    }
}

extern "C" void kernel_launch(void* const* d_in, const int* in_sizes, int n_in,
                              void* d_out, int out_size, void* d_ws, size_t ws_size,
                              hipStream_t stream) {
  const float* x        = (const float*)d_in[0];
  const float* w_router = (const float*)d_in[1];
  const float* w_gate   = (const float*)d_in[2];
  const float* w_up     = (const float*)d_in[3];
  const float* w_down   = (const float*)d_in[4];
  const float* ws_gate  = (const float*)d_in[5];
  const float* ws_up    = (const float*)d_in[6];
  const float* ws_down  = (const float*)d_in[7];

  char* ws = (char*)d_ws;
  int* hdr = (int*)ws;
  int* tok = (int*)(ws + 1024);
  float* wgt = (float*)(ws + 1024 + (size_t)KNG * KT * 4);
  const size_t hoff = 1024 + (size_t)2 * KNG * KT * 4;        // 590848
  const size_t rows = (size_t)3 * KT;                         // 24576 h-rows
  const size_t xoff = hoff + rows * KF * 2;                   // + 201326592
  const size_t woff = xoff + (size_t)KT * KD * 2;             // + 16777216
  const size_t need_fast = woff + (size_t)27 * MATELTS * 2;   // ~445.2 MB
  const size_t need_slow = xoff;                              // ~202 MB

  hipMemsetAsync(hdr, 0, 1024, stream);
  hipMemsetAsync(d_out, 0, (size_t)out_size * sizeof(float), stream);

  router_kernel<<<KT / 4, 256, 0, stream>>>(x, w_router, hdr, tok, wgt);
  finalize_kernel<<<1, 64, 0, stream>>>(hdr);

  dim3 blk(256);
  dim3 g1(KMAXRT, KF / KBN);  // (208, 32)
  dim3 g2(KMAXRT, KD / KBN);  // (208, 8)

  if (ws_size >= need_fast) {
    u16t* h = (u16t*)(ws + hoff);
    u16t* xb = (u16t*)(ws + xoff);
    u16t* wpre = (u16t*)(ws + woff);
    convert_x_kernel<<<KT * KD / (256 * 8), 256, 0, stream>>>(x, xb);
    convert_w_kernel<<<27 * 512, 256, 0, stream>>>(w_gate, w_up, w_down,
                                                   ws_gate, ws_up, ws_down, wpre);
    phase1f_kernel<<<g1, blk, 0, stream>>>(xb, wpre, hdr, tok, h);
    phase2f_kernel<<<g2, blk, 0, stream>>>(h, wpre, hdr, tok, wgt, (float*)d_out);
  } else if (ws_size >= need_slow) {
    u16t* h = (u16t*)(ws + hoff);
    phase1s_kernel<<<g1, blk, 0, stream>>>(x, w_gate, w_up, ws_gate, ws_up, hdr, tok, h);
    phase2s_kernel<<<g2, blk, 0, stream>>>(h, w_down, ws_down, hdr, tok, wgt, (float*)d_out);
  }
}

// Round 12
// 1393.325 us; speedup vs baseline: 1.8190x; 1.0356x over previous
//
#include <hip/hip_runtime.h>
#include <math.h>

// Problem constants: B=4,S=2048 -> T=8192 tokens
#define KT 8192
#define KD 1024
#define KE 8
#define KF 4096
#define KNG 9        // 8 routed experts + 1 shared "expert"
#define KBM 128
#define KBN 128
#define KBK 64       // K-tile (bf16), 2 MFMA K-steps of 32
#define KMAXRT 208   // worst-case row tiles: routed <=136, shared 64 -> 200
#define MATELTS 4194304  // D*F elements per weight matrix

typedef unsigned short u16t;
typedef __attribute__((ext_vector_type(8))) short short8v;  // 8 bf16 = 4 VGPR
typedef __attribute__((ext_vector_type(4))) float f32x4;
typedef __attribute__((ext_vector_type(4))) float fvec4;

__device__ __forceinline__ u16t f2bf(float f) {
  unsigned u = __float_as_uint(f);
  u += 0x7FFFu + ((u >> 16) & 1u);   // RNE
  return (u16t)(u >> 16);
}
__device__ __forceinline__ unsigned pack2(float lo, float hi) {
  return (unsigned)f2bf(lo) | ((unsigned)f2bf(hi) << 16);
}
// XOR-swizzled LDS index (bf16 units) for [128][64] tiles: 16B quad rotated by row&7.
__device__ __forceinline__ int swzIdx(int r, int k) {
  return r * KBK + ((((k >> 3) ^ (r & 7))) << 3) + (k & 7);
}
// global -> LDS direct copy, 16B per lane
typedef const __attribute__((address_space(1))) void* gas_ptr;
typedef __attribute__((address_space(3))) void* las_ptr;
__device__ __forceinline__ void glds16(const void* g, void* l) {
  __builtin_amdgcn_global_load_lds((gas_ptr)g, (las_ptr)l, 16, 0, 0);
}

// ---------------- Router: one wave per token (exact fp32) ----------------
__global__ void router_kernel(const float* __restrict__ x,
                              const float* __restrict__ wr,
                              int* __restrict__ hdr,
                              int* __restrict__ tok,
                              float* __restrict__ wgt,
                              int* __restrict__ rcode, int wr_rcode) {
  const int t = (blockIdx.x * blockDim.x + threadIdx.x) >> 6;
  const int lane = threadIdx.x & 63;
  if (t >= KT) return;
  const float* xr = x + (size_t)t * KD;
  float acc[KE];
#pragma unroll
  for (int e = 0; e < KE; ++e) acc[e] = 0.f;
  for (int d = lane; d < KD; d += 64) {
    float xv = xr[d];
    const float* w = wr + d * KE;
    fvec4 w0 = *(const fvec4*)(w);
    fvec4 w1 = *(const fvec4*)(w + 4);
#pragma unroll
    for (int e = 0; e < 4; ++e) {
      acc[e]     = fmaf(xv, w0[e], acc[e]);
      acc[e + 4] = fmaf(xv, w1[e], acc[e + 4]);
    }
  }
#pragma unroll
  for (int e = 0; e < KE; ++e)
#pragma unroll
    for (int off = 32; off; off >>= 1) acc[e] += __shfl_xor(acc[e], off, 64);
  if (lane == 0) {
    float mx = acc[0];
#pragma unroll
    for (int e = 1; e < KE; ++e) mx = fmaxf(mx, acc[e]);
    float p[KE]; float z = 0.f;
#pragma unroll
    for (int e = 0; e < KE; ++e) { p[e] = expf(acc[e] - mx); z += p[e]; }
    float inv = 1.f / z;
#pragma unroll
    for (int e = 0; e < KE; ++e) p[e] *= inv;
    int i1 = 0; float p1 = p[0];
#pragma unroll
    for (int e = 1; e < KE; ++e) if (p[e] > p1) { p1 = p[e]; i1 = e; }
    int i2 = -1; float p2 = -1.f;
#pragma unroll
    for (int e = 0; e < KE; ++e) if (e != i1 && p[e] > p2) { p2 = p[e]; i2 = e; }
    float s = 1.f / (p1 + p2 + 1e-8f);
    int s1 = atomicAdd(&hdr[i1], 1);
    tok[i1 * KT + s1] = t; wgt[i1 * KT + s1] = p1 * s;
    int s2 = atomicAdd(&hdr[i2], 1);
    tok[i2 * KT + s2] = t; wgt[i2 * KT + s2] = p2 * s;
    tok[KE * KT + t] = t; wgt[KE * KT + t] = 1.f;  // shared group
    if (wr_rcode) {
      rcode[2 * t]     = (i1 << 13) | s1;
      rcode[2 * t + 1] = (i2 << 13) | s2;
    }
  }
}

// ---------------- Finalize: prefix sums ----------------
__global__ void finalize_kernel(int* __restrict__ hdr) {
  if (threadIdx.x == 0 && blockIdx.x == 0) {
    hdr[KE] = KT;
    int off = 0, tb = 0;
    for (int g = 0; g < KNG; ++g) {
      hdr[16 + g] = off;
      hdr[32 + g] = tb;
      int c = hdr[g];
      off += c;
      tb += (c + KBM - 1) / KBM;
    }
    hdr[16 + KNG] = off;
    hdr[32 + KNG] = tb;
  }
}

// ---------------- Convert x: fp32 -> bf16 plain [t][k] ----------------
__global__ void convert_x_kernel(const float* __restrict__ x, u16t* __restrict__ xb) {
  const int i = (blockIdx.x * 256 + threadIdx.x) * 8;
  fvec4 a = *(const fvec4*)(x + i);
  fvec4 b = *(const fvec4*)(x + i + 4);
  uint4 o;
  o.x = pack2(a[0], a[1]); o.y = pack2(a[2], a[3]);
  o.z = pack2(b[0], b[1]); o.w = pack2(b[2], b[3]);
  *(uint4*)(xb + i) = o;
}

// ---------------- Convert weights: fp32 [K][N] -> bf16 tiled+transposed+preswizzled
// Per 128n x 64k tile: chunk c = r*8+qs (16B) holds Wt[n0+r][k0+(qs^(r&7))*8 + j].
// ft padded to 133: row-stride*8 = 1064 = 8 mod 128 -> transpose read <=2-way (free);
// was 132 -> 1056 = 0 mod 128 -> 8-way conflict.
__global__ __launch_bounds__(256) void convert_w_kernel(
    const float* __restrict__ wg, const float* __restrict__ wu,
    const float* __restrict__ wd, const float* __restrict__ sg,
    const float* __restrict__ su, const float* __restrict__ sd,
    u16t* __restrict__ wpre) {
  __shared__ float ft[64][133];
  const int m = blockIdx.x >> 9;
  const int t = blockIdx.x & 511;
  const int e = m / 3, ty = m - e * 3;
  const float* src; int K, N;
  if (ty == 2)      { K = KF; N = KD; src = (e < 8) ? wd + (size_t)e * MATELTS : sd; }
  else if (ty == 0) { K = KD; N = KF; src = (e < 8) ? wg + (size_t)e * MATELTS : sg; }
  else              { K = KD; N = KF; src = (e < 8) ? wu + (size_t)e * MATELTS : su; }
  const int ntk = K >> 6;
  const int tn = t / ntk, tk = t - tn * ntk;
  const int n0 = tn << 7, k0 = tk << 6;
  const int tid = threadIdx.x;
  const int kk0 = tid >> 5, nn4 = (tid & 31) << 2;
#pragma unroll
  for (int it = 0; it < 8; ++it) {
    int kk = kk0 + it * 8;
    fvec4 v = *(const fvec4*)(src + (size_t)(k0 + kk) * N + n0 + nn4);
    ft[kk][nn4] = v[0]; ft[kk][nn4 + 1] = v[1];
    ft[kk][nn4 + 2] = v[2]; ft[kk][nn4 + 3] = v[3];
  }
  __syncthreads();
  u16t* dst = wpre + (size_t)m * MATELTS + (size_t)t * 8192;
#pragma unroll
  for (int p = 0; p < 4; ++p) {
    int c = p * 256 + tid;
    int r = c >> 3, qs = c & 7, kq = qs ^ (r & 7);
    uint4 o;
    o.x = pack2(ft[kq * 8 + 0][r], ft[kq * 8 + 1][r]);
    o.y = pack2(ft[kq * 8 + 2][r], ft[kq * 8 + 3][r]);
    o.z = pack2(ft[kq * 8 + 4][r], ft[kq * 8 + 5][r]);
    o.w = pack2(ft[kq * 8 + 6][r], ft[kq * 8 + 7][r]);
    *(uint4*)(dst + c * 8) = o;
  }
}

// ---------------- Phase 1: h = silu(X@Wg)*(X@Wu), glds staging ----------------
// launch_bounds (256,3): occupancy probe — LDS 48.5KB permits 3 blocks/CU.
__global__ __launch_bounds__(256, 3) void phase1f_kernel(
    const u16t* __restrict__ xb, const u16t* __restrict__ wpre,
    const int* __restrict__ hdr, const int* __restrict__ tok,
    u16t* __restrict__ h) {
  const int* tb = hdr + 32;
  const int rt = blockIdx.x;
  if (rt >= tb[KNG]) return;
  int g = 0;
  while (rt >= tb[g + 1]) ++g;
  const int ng = hdr[g];
  const int row0 = (rt - tb[g]) * KBM;
  const int offg = hdr[16 + g];
  const int f0 = blockIdx.y * KBN;

  __shared__ u16t As[KBM * KBK];
  __shared__ u16t Bg[KBN * KBK];
  __shared__ u16t Bu[KBN * KBK];
  __shared__ int toks_s[KBM];

  const int tid = threadIdx.x;
  if (tid < KBM) {
    int gr = row0 + tid;
    if (gr >= ng) gr = ng - 1;
    toks_s[tid] = tok[g * KT + gr];
  }
  __syncthreads();

  const int lane = tid & 63, wv = tid >> 6;
  const int wm = (wv & 1) * 64, wn = (wv >> 1) * 64;
  const int lr = lane & 15, lq = lane >> 4;
  const int cr = tid >> 3;           // A-chunk row (c4 adds 32)
  const int cq = tid & 7;            // A-chunk swizzled quad
  const int wvo = (tid & 192) * 8;   // wave chunk base (elements)

  const u16t* gp = wpre + (size_t)(3 * g) * MATELTS + (size_t)(f0 >> 7) * 16 * 8192;
  const u16t* up = gp + MATELTS;

  f32x4 accg[4][4], accu[4][4];
#pragma unroll
  for (int i = 0; i < 4; ++i)
#pragma unroll
    for (int j = 0; j < 4; ++j) { accg[i][j] = (f32x4)(0.f); accu[i][j] = (f32x4)(0.f); }

  for (int k0i = 0; k0i < KD / KBK; ++k0i) {
    const u16t* gt = gp + (size_t)k0i * 8192;
    const u16t* ut = up + (size_t)k0i * 8192;
#pragma unroll
    for (int c4 = 0; c4 < 4; ++c4) {
      glds16(gt + (c4 * 256 + tid) * 8, (u16t*)Bg + c4 * 2048 + wvo);
      glds16(ut + (c4 * 256 + tid) * 8, (u16t*)Bu + c4 * 2048 + wvo);
      int r = c4 * 32 + cr;
      glds16(xb + (size_t)toks_s[r] * KD + k0i * KBK + ((cq ^ (r & 7)) << 3),
             (u16t*)As + c4 * 2048 + wvo);
    }
    __syncthreads();
#pragma unroll
    for (int kk = 0; kk < 2; ++kk) {
      const int kb = kk * 32 + lq * 8;
      short8v av[4];
#pragma unroll
      for (int mi = 0; mi < 4; ++mi)
        av[mi] = *(const short8v*)&As[swzIdx(wm + mi * 16 + lr, kb)];
#pragma unroll
      for (int ni = 0; ni < 4; ++ni) {
        short8v bgv = *(const short8v*)&Bg[swzIdx(wn + ni * 16 + lr, kb)];
        short8v buv = *(const short8v*)&Bu[swzIdx(wn + ni * 16 + lr, kb)];
#pragma unroll
        for (int mi = 0; mi < 4; ++mi) {
          accg[mi][ni] = __builtin_amdgcn_mfma_f32_16x16x32_bf16(av[mi], bgv, accg[mi][ni], 0, 0, 0);
          accu[mi][ni] = __builtin_amdgcn_mfma_f32_16x16x32_bf16(av[mi], buv, accu[mi][ni], 0, 0, 0);
        }
      }
    }
    __syncthreads();
  }

#pragma unroll
  for (int mi = 0; mi < 4; ++mi)
#pragma unroll
    for (int r = 0; r < 4; ++r) {
      int gr = row0 + wm + mi * 16 + lq * 4 + r;
      if (gr >= ng) continue;
      u16t* hp = h + (size_t)(offg + gr) * KF + f0 + wn + lr;
#pragma unroll
      for (int ni = 0; ni < 4; ++ni) {
        float gv = accg[mi][ni][r];
        float uv = accu[mi][ni][r];
        float sv = gv / (1.f + __expf(-gv));
        hp[ni * 16] = f2bf(sv * uv);
      }
    }
}

// ---------------- Phase 2: partial = w * (h @ Wd), glds staging ----------------
// use_wpart: coalesced stores to wpart (combine sums later). Else: atomic into out.
__global__ __launch_bounds__(256, 3) void phase2f_kernel(
    const u16t* __restrict__ h, const u16t* __restrict__ wpre,
    const int* __restrict__ hdr, const int* __restrict__ tok,
    const float* __restrict__ wgt, float* __restrict__ out,
    float* __restrict__ wpart, int use_wpart) {
  const int* tb = hdr + 32;
  const int rt = blockIdx.x;
  if (rt >= tb[KNG]) return;
  int g = 0;
  while (rt >= tb[g + 1]) ++g;
  const int ng = hdr[g];
  const int row0 = (rt - tb[g]) * KBM;
  const int offg = hdr[16 + g];
  const int d0 = blockIdx.y * KBN;

  __shared__ u16t As[KBM * KBK];
  __shared__ u16t Bs[KBN * KBK];
  __shared__ int toks_s[KBM];
  __shared__ float wgts_s[KBM];

  const int tid = threadIdx.x;
  if (tid < KBM) {
    int gr = row0 + tid;
    int grc = (gr >= ng) ? ng - 1 : gr;
    toks_s[tid] = tok[g * KT + grc];
    wgts_s[tid] = wgt[g * KT + grc];
  }
  __syncthreads();

  const int lane = tid & 63, wv = tid >> 6;
  const int wm = (wv & 1) * 64, wn = (wv >> 1) * 64;
  const int lr = lane & 15, lq = lane >> 4;
  const int cr = tid >> 3;
  const int cq = tid & 7;
  const int wvo = (tid & 192) * 8;

  const u16t* dp = wpre + (size_t)(3 * g + 2) * MATELTS + (size_t)(d0 >> 7) * 64 * 8192;

  f32x4 acc[4][4];
#pragma unroll
  for (int i = 0; i < 4; ++i)
#pragma unroll
    for (int j = 0; j < 4; ++j) acc[i][j] = (f32x4)(0.f);

  for (int k0i = 0; k0i < KF / KBK; ++k0i) {
    const u16t* dt = dp + (size_t)k0i * 8192;
#pragma unroll
    for (int c4 = 0; c4 < 4; ++c4) {
      glds16(dt + (c4 * 256 + tid) * 8, (u16t*)Bs + c4 * 2048 + wvo);
      int r = c4 * 32 + cr;
      int grow = row0 + r;
      if (grow >= ng) grow = ng - 1;
      glds16(h + (size_t)(offg + grow) * KF + k0i * KBK + ((cq ^ (r & 7)) << 3),
             (u16t*)As + c4 * 2048 + wvo);
    }
    __syncthreads();
#pragma unroll
    for (int kk = 0; kk < 2; ++kk) {
      const int kb = kk * 32 + lq * 8;
      short8v av[4];
#pragma unroll
      for (int mi = 0; mi < 4; ++mi)
        av[mi] = *(const short8v*)&As[swzIdx(wm + mi * 16 + lr, kb)];
#pragma unroll
      for (int ni = 0; ni < 4; ++ni) {
        short8v bv = *(const short8v*)&Bs[swzIdx(wn + ni * 16 + lr, kb)];
#pragma unroll
        for (int mi = 0; mi < 4; ++mi)
          acc[mi][ni] = __builtin_amdgcn_mfma_f32_16x16x32_bf16(av[mi], bv, acc[mi][ni], 0, 0, 0);
      }
    }
    __syncthreads();
  }

  if (use_wpart) {
#pragma unroll
    for (int mi = 0; mi < 4; ++mi)
#pragma unroll
      for (int r = 0; r < 4; ++r) {
        int row = wm + mi * 16 + lq * 4 + r;
        int gr = row0 + row;
        if (gr >= ng) continue;
        float w = wgts_s[row];
        float* op = wpart + (size_t)(offg + gr) * KD + d0 + wn + lr;
#pragma unroll
        for (int ni = 0; ni < 4; ++ni)
          op[ni * 16] = acc[mi][ni][r] * w;
      }
  } else {
#pragma unroll
    for (int mi = 0; mi < 4; ++mi)
#pragma unroll
      for (int r = 0; r < 4; ++r) {
        int row = wm + mi * 16 + lq * 4 + r;
        int gr = row0 + row;
        if (gr >= ng) continue;
        int t = toks_s[row];
        float w = wgts_s[row];
        float* op = out + (size_t)t * KD + d0 + wn + lr;
#pragma unroll
        for (int ni = 0; ni < 4; ++ni)
          atomicAdd(op + ni * 16, acc[mi][ni][r] * w);
      }
  }
}

// ---------------- Combine: out[t] = wpart[shared] + wpart[r1] + wpart[r2] ----------------
__global__ void combine_kernel(const float* __restrict__ wpart,
                               const int* __restrict__ hdr,
                               const int* __restrict__ rcode,
                               float* __restrict__ out) {
  const int t = blockIdx.x;
  const int d = threadIdx.x * 4;
  const int* off = hdr + 16;
  const int c1 = rcode[2 * t], c2 = rcode[2 * t + 1];
  const size_t r1 = (size_t)(off[c1 >> 13] + (c1 & 8191)) * KD;
  const size_t r2 = (size_t)(off[c2 >> 13] + (c2 & 8191)) * KD;
  const size_t rs = (size_t)(off[KE] + t) * KD;
  fvec4 a = *(const fvec4*)(wpart + r1 + d);
  fvec4 b = *(const fvec4*)(wpart + r2 + d);
  fvec4 c = *(const fvec4*)(wpart + rs + d);
  fvec4 o;
#pragma unroll
  for (int j = 0; j < 4; ++j) o[j] = a[j] + b[j] + c[j];
  *(fvec4*)(out + (size_t)t * KD + d) = o;
}

extern "C" void kernel_launch(void* const* d_in, const int* in_sizes, int n_in,
                              void* d_out, int out_size, void* d_ws, size_t ws_size,
                              hipStream_t stream) {
  const float* x        = (const float*)d_in[0];
  const float* w_router = (const float*)d_in[1];
  const float* w_gate   = (const float*)d_in[2];
  const float* w_up     = (const float*)d_in[3];
  const float* w_down   = (const float*)d_in[4];
  const float* ws_gate  = (const float*)d_in[5];
  const float* ws_up    = (const float*)d_in[6];
  const float* ws_down  = (const float*)d_in[7];

  char* ws = (char*)d_ws;
  int* hdr = (int*)ws;
  int* tok = (int*)(ws + 1024);
  float* wgt = (float*)(ws + 1024 + (size_t)KNG * KT * 4);
  const size_t hoff  = 1024 + (size_t)2 * KNG * KT * 4;        // 590848
  const size_t rows  = (size_t)3 * KT;                         // 24576 h-rows
  const size_t xoff  = hoff + rows * KF * 2;                   // + 201326592
  const size_t woff  = xoff + (size_t)KT * KD * 2;             // + 16777216
  const size_t rcoff = woff + (size_t)27 * MATELTS * 2;        // + 226492416 (~445 MB)
  const size_t wpoff = rcoff + 65536;
  const size_t need_fast = rcoff;                              // atomic-epilogue path
  const size_t need_comb = wpoff + rows * KD * 4;              // + 100.7 MB (~546 MB)

  const int use_comb = (ws_size >= need_comb) ? 1 : 0;

  u16t* h     = (u16t*)(ws + hoff);
  u16t* xb    = (u16t*)(ws + xoff);
  u16t* wpre  = (u16t*)(ws + woff);
  int*  rcode = (int*)(ws + rcoff);
  float* wpart = (float*)(ws + wpoff);

  hipMemsetAsync(hdr, 0, 1024, stream);
  if (!use_comb)
    hipMemsetAsync(d_out, 0, (size_t)out_size * sizeof(float), stream);

  router_kernel<<<KT / 4, 256, 0, stream>>>(x, w_router, hdr, tok, wgt, rcode, use_comb);
  finalize_kernel<<<1, 64, 0, stream>>>(hdr);

  if (ws_size >= need_fast) {
    dim3 blk(256);
    dim3 g1(KMAXRT, KF / KBN);  // (208, 32)
    dim3 g2(KMAXRT, KD / KBN);  // (208, 8)
    convert_x_kernel<<<KT * KD / (256 * 8), 256, 0, stream>>>(x, xb);
    convert_w_kernel<<<27 * 512, 256, 0, stream>>>(w_gate, w_up, w_down,
                                                   ws_gate, ws_up, ws_down, wpre);
    phase1f_kernel<<<g1, blk, 0, stream>>>(xb, wpre, hdr, tok, h);
    phase2f_kernel<<<g2, blk, 0, stream>>>(h, wpre, hdr, tok, wgt,
                                           (float*)d_out, wpart, use_comb);
    if (use_comb)
      combine_kernel<<<KT, 256, 0, stream>>>(wpart, hdr, rcode, (float*)d_out);
  }
  // ws < 445 MB never observed (rounds 8/10 ran the fast path) — no slow fallback.
}